// Round 1
// baseline (291.316 us; speedup 1.0000x reference)
//
#include <hip/hip_runtime.h>
#include <math.h>

// KoLeo loss: dist_i = sqrt(2 - 2*max_{j!=i} <fhat_i, fhat_j>); loss = -mean(log(dist+1e-8))
// Row/col-max of Gram via MX-scaled fp8 MFMA (16x16x128 f8f6f4, unit scales).
// R10: port of the verified 256^2 counted-vmcnt phase schedule (learn_hip m201
// class: T2 swizzle + T3/T4 counted pipeline + T5 setprio). 8 waves (2Mx4N),
// per-wave 128x64 output, LDS 128 KiB double-buffered, 1 block/CU.
// Staging chunks are deadline-ordered via bit-permuted LDS row slots:
//   A chunk0 = rows {0-63,128-191}   (needed phase 1)   issued phase 1
//   B chunk0 = rows {first 32 of each wj quarter} (ph1) issued phase 2
//   B chunk1 = rows {last 32 of each quarter}     (ph2) issued phase 3
//   A chunk1 = rows {64-127,192-255}              (ph3) issued phase 4
// Wait ladder (FIFO, 2 loads/chunk): vmcnt(4) at ends of phases 1,2,4; none at
// phase 3; epilogue drains 2 -> 0. Never vmcnt(0) in the main loop.
// Features pre-scaled x16 before e4m3 cast; raw dots carry x256, folded out in
// row_reduce (max is monotone). Each tile yields row-max AND col-max.

#define N_ROWS 16384
#define DIM 1024
#define BT 256
#define NT (N_ROWS / BT)          // 64
#define NKT (DIM / 128)           // 8 K-tiles (128 fp8 elements each)
#define NBLK (NT * (NT + 1) / 2)  // 2080 (divisible by 8 -> simple XCD swizzle)

typedef int   i32x4 __attribute__((ext_vector_type(4)));
typedef int   i32x8 __attribute__((ext_vector_type(8)));
typedef float f32x4 __attribute__((ext_vector_type(4)));

__device__ __forceinline__ void async16(const void* g, void* l) {
  __builtin_amdgcn_global_load_lds(
      (__attribute__((address_space(1))) const void*)g,
      (__attribute__((address_space(3))) void*)l, 16, 0, 0);
}

// Raw barrier with compile-time motion fences (rule #18/#21: hipcc will hoist
// reg-only MFMA past inline-asm waits and float LDS loads across s_barrier).
#define S_BAR()                          \
  do {                                   \
    __builtin_amdgcn_sched_barrier(0);   \
    __builtin_amdgcn_s_barrier();        \
    __builtin_amdgcn_sched_barrier(0);   \
  } while (0)
#define WAIT_VM(N) asm volatile("s_waitcnt vmcnt(" #N ")" ::: "memory")
#define WAIT_LGKM()                                        \
  do {                                                     \
    asm volatile("s_waitcnt lgkmcnt(0)" ::: "memory");     \
    __builtin_amdgcn_sched_barrier(0);                     \
  } while (0)

// ---------------------------------------------------------------- normalize
__global__ __launch_bounds__(256) void normalize_kernel(
    const float* __restrict__ in, unsigned int* __restrict__ outp) {
  const int row = blockIdx.x;
  const int t = threadIdx.x;  // 256 threads x 4 floats
  const float4 v = ((const float4*)(in + (size_t)row * DIM))[t];
  float ss = v.x * v.x + v.y * v.y + v.z * v.z + v.w * v.w;
#pragma unroll
  for (int s = 1; s < 64; s <<= 1) ss += __shfl_xor(ss, s, 64);
  __shared__ float wsum[4];
  const int wave = t >> 6, lane = t & 63;
  if (lane == 0) wsum[wave] = ss;
  __syncthreads();
  const float tot = wsum[0] + wsum[1] + wsum[2] + wsum[3];
  const float scale = 16.f / fmaxf(sqrtf(tot), 1e-12f);
  unsigned int p = __builtin_amdgcn_cvt_pk_fp8_f32(v.x * scale, v.y * scale, 0, false);
  p = __builtin_amdgcn_cvt_pk_fp8_f32(v.z * scale, v.w * scale, p, true);
  outp[(size_t)row * (DIM / 4) + t] = p;
}

// -------------------------------------------------- staging (pre-swizzled src)
// LDS row slot s (128 B) stores logical k-granule g at physical slot g^(s&7).
// A-panel slot->global-row: swap bits 6<->7 of the row index.
__device__ __forceinline__ void stage_chunkA(const unsigned char* __restrict__ Fp,
                                             unsigned char* buf, int k0, int chunk,
                                             int tid, int lane) {
#pragma unroll
  for (int rnd = 0; rnd < 2; ++rnd) {
    const int flatb = rnd * 512 + (tid & ~63);  // wave-uniform granule base
    const int flat = flatb + lane;
    const int slot = chunk * 128 + (flat >> 3);
    const int lg = (flat & 7) ^ (slot & 7);  // logical k-granule
    const int grow = (slot & 63) + (((slot >> 7) & 1) << 6) + (((slot >> 6) & 1) << 7);
    async16(Fp + (size_t)grow * DIM + k0 + (lg << 4),
            buf + chunk * 16384 + flatb * 16);
  }
}
// B-panel slot->global-row: rotate {bit7 <- bit5, bits6:5 <- bits7:6}.
__device__ __forceinline__ void stage_chunkB(const unsigned char* __restrict__ Fp,
                                             unsigned char* buf, int k0, int chunk,
                                             int tid, int lane) {
#pragma unroll
  for (int rnd = 0; rnd < 2; ++rnd) {
    const int flatb = rnd * 512 + (tid & ~63);
    const int flat = flatb + lane;
    const int slot = chunk * 128 + (flat >> 3);
    const int lg = (flat & 7) ^ (slot & 7);
    const int grow = (slot & 31) + (((slot >> 5) & 3) << 6) + (((slot >> 7) & 1) << 5);
    async16(Fp + (size_t)grow * DIM + k0 + (lg << 4),
            buf + chunk * 16384 + flatb * 16);
  }
}

// lane reads logical granules 2q,2q+1 of a slot; x0/x1 = swizzled byte offsets
#define READ_FRAG(dst, buf, slot)                        \
  do {                                                   \
    const unsigned char* _b = (buf) + (size_t)(slot) * 128; \
    i32x4 _lo = *(const i32x4*)(_b + x0);                \
    i32x4 _hi = *(const i32x4*)(_b + x1);                \
    dst = __builtin_shufflevector(_lo, _hi, 0, 1, 2, 3, 4, 5, 6, 7); \
  } while (0)

#define MFMA_QUAD(MB, NB)                                                     \
  do {                                                                        \
    __builtin_amdgcn_s_setprio(1);                                            \
    _Pragma("unroll") for (int mi = 0; mi < 4; ++mi) {                        \
      _Pragma("unroll") for (int ni = 0; ni < 2; ++ni) {                      \
        acc[(MB) + mi][(NB) + ni] =                                           \
            __builtin_amdgcn_mfma_scale_f32_16x16x128_f8f6f4(                 \
                afr[mi], bfr[(NB) + ni], acc[(MB) + mi][(NB) + ni], 0, 0,     \
                0, 0x7F7F7F7F, 0, 0x7F7F7F7F);                                \
      }                                                                       \
    }                                                                         \
    __builtin_amdgcn_s_setprio(0);                                            \
  } while (0)

// -------------------------------------------------- Gram row/col-max GEMM
__global__ __launch_bounds__(512, 2) void gemm_rowmax(
    const unsigned char* __restrict__ F, float* __restrict__ partial) {
  // XCD-chunked bijective swizzle (2080 % 8 == 0), then triangular decode
  int bid = blockIdx.x;
  bid = (bid & 7) * (NBLK / 8) + (bid >> 3);
  double disc = (double)(2 * NT + 1) * (2 * NT + 1) - 8.0 * (double)bid;
  int it = (int)(((2 * NT + 1) - sqrt(disc)) * 0.5);
  if (it > NT - 1) it = NT - 1;
  while (it > 0 && it * NT - it * (it - 1) / 2 > bid) --it;
  while ((it + 1) * NT - (it + 1) * it / 2 <= bid) ++it;
  const int jt = it + (bid - (it * NT - it * (it - 1) / 2));

  __shared__ __align__(16) unsigned char sA[2][BT * 128];  // 64 KiB
  __shared__ __align__(16) unsigned char sB[2][BT * 128];  // 64 KiB

  const int ibase = it * BT, jbase = jt * BT;
  const int tid = threadIdx.x;
  const int wave = tid >> 6, lane = tid & 63;
  const int wi = wave >> 2, wj = wave & 3;  // 2x4 wave grid, 128x64 each
  const int quad = lane >> 4, r16 = lane & 15;

  const unsigned char* FA = F + (size_t)ibase * DIM;
  const unsigned char* FB = F + (size_t)jbase * DIM;

  // loop-invariant read addressing (slot&7 == r16&7 for every slot we touch)
  const int x0 = ((2 * quad) ^ (r16 & 7)) << 4;
  const int x1 = ((2 * quad + 1) ^ (r16 & 7)) << 4;
  const int aslot0 = wi * 64 + r16;  // + mi*16 (mi<4); +128 for mi>=4
  const int bslot0 = wj * 32 + r16;  // + (ni&1)*16 + ((ni>>1)&1)*128

  f32x4 acc[8][4] = {};  // [mi][ni] 16x16 tiles
  i32x8 afr[4], bfr[4];

  // prologue: stage tile 0 in deadline order; keep 2 chunks in flight
  stage_chunkA(FA, sA[0], 0, 0, tid, lane);
  stage_chunkB(FB, sB[0], 0, 0, tid, lane);
  stage_chunkB(FB, sB[0], 0, 1, tid, lane);
  stage_chunkA(FA, sA[0], 0, 1, tid, lane);
  WAIT_VM(4);
  S_BAR();

#pragma unroll 1
  for (int kt = 0; kt < NKT - 1; ++kt) {
    unsigned char* cA = sA[kt & 1];
    unsigned char* cB = sB[kt & 1];
    unsigned char* nA = sA[(kt & 1) ^ 1];
    unsigned char* nB = sB[(kt & 1) ^ 1];
    const int k0n = (kt + 1) * 128;

    // ---- phase 1: frags A(mi0-3), B(ni0-1); prefetch A chunk0 (next)
#pragma unroll
    for (int mi = 0; mi < 4; ++mi) READ_FRAG(afr[mi], cA, aslot0 + mi * 16);
    READ_FRAG(bfr[0], cB, bslot0);
    READ_FRAG(bfr[1], cB, bslot0 + 16);
    stage_chunkA(FA, nA, k0n, 0, tid, lane);
    WAIT_VM(4);
    S_BAR();
    WAIT_LGKM();
    MFMA_QUAD(0, 0);
    S_BAR();
    // ---- phase 2: frags B(ni2-3); prefetch B chunk0 (next)
    READ_FRAG(bfr[2], cB, bslot0 + 128);
    READ_FRAG(bfr[3], cB, bslot0 + 144);
    stage_chunkB(FB, nB, k0n, 0, tid, lane);
    WAIT_VM(4);
    S_BAR();
    WAIT_LGKM();
    MFMA_QUAD(0, 2);
    S_BAR();
    // ---- phase 3: frags A(mi4-7); prefetch B chunk1 (next); no vm wait
#pragma unroll
    for (int mi = 0; mi < 4; ++mi) READ_FRAG(afr[mi], cA, 128 + aslot0 + mi * 16);
    stage_chunkB(FB, nB, k0n, 1, tid, lane);
    S_BAR();
    WAIT_LGKM();
    MFMA_QUAD(4, 0);
    S_BAR();
    // ---- phase 4: prefetch A chunk1 (next); publish next-tile chunk0s
    stage_chunkA(FA, nA, k0n, 1, tid, lane);
    WAIT_VM(4);
    S_BAR();
    MFMA_QUAD(4, 2);
    S_BAR();
  }

  // ---- final K-tile (no prefetch; drain 2 -> 0)
  {
    unsigned char* cA = sA[(NKT - 1) & 1];
    unsigned char* cB = sB[(NKT - 1) & 1];
#pragma unroll
    for (int mi = 0; mi < 4; ++mi) READ_FRAG(afr[mi], cA, aslot0 + mi * 16);
    READ_FRAG(bfr[0], cB, bslot0);
    READ_FRAG(bfr[1], cB, bslot0 + 16);
    WAIT_VM(2);
    S_BAR();
    WAIT_LGKM();
    MFMA_QUAD(0, 0);
    S_BAR();
    READ_FRAG(bfr[2], cB, bslot0 + 128);
    READ_FRAG(bfr[3], cB, bslot0 + 144);
    WAIT_VM(0);
    S_BAR();
    WAIT_LGKM();
    MFMA_QUAD(0, 2);
    S_BAR();
#pragma unroll
    for (int mi = 0; mi < 4; ++mi) READ_FRAG(afr[mi], cA, 128 + aslot0 + mi * 16);
    S_BAR();
    WAIT_LGKM();
    MFMA_QUAD(4, 0);
    S_BAR();
    MFMA_QUAD(4, 2);
  }

  // ---------------- epilogue: row/col max (LDS aliased over dead sA)
  __syncthreads();
  float(*red)[4] = (float(*)[4]) & sA[0][0];            // [256][4] over wj
  float(*redc)[2] = (float(*)[2])(&sA[0][0] + 4096);    // [256][2] over wi

  // C/D layout (16x16): col = lane&15, row = quad*4 + reg.
#pragma unroll
  for (int mi = 0; mi < 8; ++mi) {
#pragma unroll
    for (int r = 0; r < 4; ++r) {
      const int rl = wi * 128 + mi * 16 + quad * 4 + r;
      const int rowg = ibase + rl;
      float m = -INFINITY;
#pragma unroll
      for (int ni = 0; ni < 4; ++ni) {
        const int colg = jbase + wj * 64 + ni * 16 + r16;
        const float v = acc[mi][ni][r];
        m = (rowg == colg) ? m : fmaxf(m, v);
      }
#pragma unroll
      for (int s = 1; s < 16; s <<= 1) m = fmaxf(m, __shfl_xor(m, s, 64));
      if (r16 == 0) red[rl][wj] = m;
    }
  }
  if (it != jt) {  // col-max (off-diagonal tiles: no diag elements present)
#pragma unroll
    for (int ni = 0; ni < 4; ++ni) {
      float m = -INFINITY;
#pragma unroll
      for (int mi = 0; mi < 8; ++mi)
#pragma unroll
        for (int r = 0; r < 4; ++r) m = fmaxf(m, acc[mi][ni][r]);
      m = fmaxf(m, __shfl_xor(m, 16, 64));
      m = fmaxf(m, __shfl_xor(m, 32, 64));
      if (quad == 0) redc[wj * 64 + ni * 16 + r16][wi] = m;
    }
  }
  __syncthreads();
  if (tid < BT) {
    const float a = fmaxf(red[tid][0], red[tid][1]);
    const float b = fmaxf(red[tid][2], red[tid][3]);
    partial[(size_t)jt * N_ROWS + ibase + tid] = fmaxf(a, b);
  } else if (it != jt) {
    const int c = tid - BT;
    partial[(size_t)it * N_ROWS + jbase + c] = fmaxf(redc[c][0], redc[c][1]);
  }
}

// ------------------------------------------------------------- reductions
__global__ __launch_bounds__(256) void row_reduce(
    const float* __restrict__ partial, float* __restrict__ blocksum) {
  const int r = blockIdx.x * 256 + threadIdx.x;
  float m = -INFINITY;
  for (int p = 0; p < NT; ++p)
    m = fmaxf(m, partial[(size_t)p * N_ROWS + r]);
  // raw dot carries x256 (features scaled x16): 2 - 2*(m/256) = 2 - m/128
  const float d2 = fmaxf(2.f - m * (1.f / 128.f), 0.f);
  float term = logf(sqrtf(d2) + 1e-8f);
#pragma unroll
  for (int s = 1; s < 64; s <<= 1) term += __shfl_xor(term, s, 64);
  __shared__ float wsum[4];
  const int wave = threadIdx.x >> 6, lane = threadIdx.x & 63;
  if (lane == 0) wsum[wave] = term;
  __syncthreads();
  if (threadIdx.x == 0)
    blocksum[blockIdx.x] = wsum[0] + wsum[1] + wsum[2] + wsum[3];
}

__global__ void finalize(const float* __restrict__ blocksum,
                         float* __restrict__ out) {
  float v = blocksum[threadIdx.x];
#pragma unroll
  for (int s = 1; s < 64; s <<= 1) v += __shfl_xor(v, s, 64);
  if (threadIdx.x == 0) out[0] = -v / (float)N_ROWS;
}

// ---------------------------------------------------------------- launcher
extern "C" void kernel_launch(void* const* d_in, const int* in_sizes, int n_in,
                              void* d_out, int out_size, void* d_ws, size_t ws_size,
                              hipStream_t stream) {
  const float* feats = (const float*)d_in[0];
  float* out = (float*)d_out;
  char* ws = (char*)d_ws;

  // ws: [0,16MB) fp8 features; [16MB,20MB) partial [64][16384] f32; then sums.
  unsigned char* f8 = (unsigned char*)ws;
  float* partial = (float*)(ws + (size_t)N_ROWS * DIM);
  float* blocksum =
      (float*)(ws + (size_t)N_ROWS * DIM + (size_t)NT * N_ROWS * 4);

  normalize_kernel<<<N_ROWS, 256, 0, stream>>>(feats, (unsigned int*)f8);
  gemm_rowmax<<<NBLK, 512, 0, stream>>>(f8, partial);
  row_reduce<<<N_ROWS / 256, 256, 0, stream>>>(partial, blocksum);
  finalize<<<1, 64, 0, stream>>>(blocksum, out);
}